// Round 5
// baseline (179.277 us; speedup 1.0000x reference)
//
#include <hip/hip_runtime.h>
#include <hip/hip_bf16.h>

// y[b,i,j,u] = relu( sum_{c,h} w[u,c,i,h] * x[b,h,j,c] )
// B=16,H=64,W=64,C=64,U=128
// GEMM: M=(b,j)=1024, N=(i,u)=8192 (n=i*128+u), K=(h,c)=4096, kappa=h*64+c.
//
// Pass 1a: Xb[b][h][j][c] = bf16(x)                      (8.39 MB, ws+0)
// Pass 1b: Wb[i][u][h][c] = bf16(w[u][c][i][h])          (64 MB,  ws+8388608)
// Pass 2 : BM=BN=128, BK=64, 4 waves (2x2), grid 512 = 2 blocks/CU.
//          A-fragments DIRECT from global (Xb is L2/L3-resident), prefetched
//          one K-step ahead into a double register buffer. B triple-buffered
//          in LDS via global_load_lds + source-side XOR swizzle (T2), counted
//          s_waitcnt vmcnt(4) (T4), round-3 proven 2-phase barrier skeleton
//          with setprio (T5), XCD-bijective block swizzle (T1).

typedef __attribute__((ext_vector_type(4))) float f32x4;
typedef __attribute__((ext_vector_type(8))) short bf16x8;
typedef __attribute__((ext_vector_type(4))) unsigned int u32x4;
typedef __attribute__((ext_vector_type(2))) unsigned int u32x2;
typedef unsigned short ushort_t;

static __device__ __forceinline__ unsigned int cvt_pk_bf16(float lo, float hi) {
  unsigned int r;
  asm("v_cvt_pk_bf16_f32 %0, %1, %2" : "=v"(r) : "v"(lo), "v"(hi));
  return r;
}

static __device__ __forceinline__ void async_copy16(void* lds, const void* g) {
  __builtin_amdgcn_global_load_lds(
      (const __attribute__((address_space(1))) unsigned int*)g,
      (__attribute__((address_space(3))) unsigned int*)lds, 16, 0, 0);
}

// ---------------- Pass 1a: x f32 -> bf16 (straight) ----------------
__global__ __launch_bounds__(256)
void conv_x(const float* __restrict__ X, ushort_t* __restrict__ Xb, int n4) {
  int idx = blockIdx.x * 256 + threadIdx.x;
  const int stride = gridDim.x * 256;
  for (; idx < n4; idx += stride) {
    f32x4 v = ((const f32x4*)X)[idx];
    u32x2 o;
    o.x = cvt_pk_bf16(v.x, v.y);
    o.y = cvt_pk_bf16(v.z, v.w);
    ((u32x2*)Xb)[idx] = o;
  }
}

// ---------------- Pass 1b: w[u][c][i][h] -> Wb[i][u][h][c] bf16 ----------------
__global__ __launch_bounds__(256)
void conv_w(const float* __restrict__ W, ushort_t* __restrict__ Wb) {
  __shared__ float T[64][65];  // [c][h], +1 pad
  const int bid = blockIdx.x;       // 8192 blocks = u*64 + i
  const int u = bid >> 6;
  const int i = bid & 63;
  const int t = threadIdx.x;

  const int hq = t & 15;            // 16B chunk of h-row
  const int c4 = t >> 4;            // 0..15
  const float* base = W + (((size_t)u * 64) * 64 + i) * 64;  // + c*4096 + h
#pragma unroll
  for (int it = 0; it < 4; ++it) {
    const int c = it * 16 + c4;
    f32x4 v = *(const f32x4*)(base + (size_t)c * 4096 + hq * 4);
    *(f32x4*)&T[c][hq * 4] = v;
  }
  __syncthreads();

  const int h = t >> 2;
  const int c0 = (t & 3) * 16;
  unsigned int pk[8];
#pragma unroll
  for (int q = 0; q < 8; ++q)
    pk[q] = cvt_pk_bf16(T[c0 + 2 * q][h], T[c0 + 2 * q + 1][h]);
  ushort_t* out = Wb + (((size_t)i * 128 + u) * 64 + h) * 64 + c0;
  ((u32x4*)out)[0] = *(u32x4*)&pk[0];
  ((u32x4*)out)[1] = *(u32x4*)&pk[4];
}

// ---------------- Pass 2: bf16 GEMM, A-direct + 2-block stagger ----------------
__global__ __launch_bounds__(256, 2)
void gemm4(const ushort_t* __restrict__ Xb, const ushort_t* __restrict__ Wb,
           float* __restrict__ O) {
  __shared__ ushort_t Bs[3][128 * 64];  // 16KB each, XOR-swizzled rows

  const int tid = threadIdx.x;
  const int lane = tid & 63;
  const int wid = tid >> 6;         // 4 waves
  const int wm = wid >> 1;          // 0..1 : 64-row m slab
  const int wn = wid & 1;           // 0..1 : 64-col n slab

  const int bid = blockIdx.x;       // 512 blocks; XCD-bijective swizzle
  const int wg = (bid & 7) * 64 + (bid >> 3);
  const int mt = wg & 7;            // 8 m-tiles of 128
  const int nt = wg >> 3;           // 64 n-tiles of 128 == output i

  const char* WbB = (const char*)Wb;

  // ---- B staging geometry: LDS dest lane-linear, source carries the XOR ----
  int b_dst[4]; size_t b_src[4];
#pragma unroll
  for (int it = 0; it < 4; ++it) {
    const int flat = it * 4096 + tid * 16;
    const int nl = flat >> 7;             // n_local == u, 0..127
    const int p = (flat >> 4) & 7;
    b_dst[it] = flat;
    b_src[it] = (size_t)(nt * 128 + nl) * 8192 + ((p ^ (nl & 7)) << 4);
  }

  // ---- B fragment ds_read offsets ----
  int b_ro[2][4];
#pragma unroll
  for (int kk = 0; kk < 2; ++kk)
#pragma unroll
    for (int f = 0; f < 4; ++f) {
      const int row = wn * 64 + f * 16 + (lane & 15);
      const int byte0 = row * 128 + kk * 64 + (lane >> 4) * 16;
      b_ro[kk][f] = byte0 ^ ((row & 7) << 4);
    }

  // ---- A global fragment bases (element offsets into Xb) ----
  // m = mt*128 + wm*64 + mf*16 + (lane&15) -> b = mt*2+wm, j = mf*16+(lane&15)
  // addr = b*262144 + t*4096 + j*64 + kk*32 + (lane>>4)*8
  size_t a_g[4];
#pragma unroll
  for (int mf = 0; mf < 4; ++mf)
    a_g[mf] = (size_t)(mt * 2 + wm) * 262144 +
              (size_t)(mf * 16 + (lane & 15)) * 64 + (lane >> 4) * 8;

  f32x4 acc[4][4];
#pragma unroll
  for (int i = 0; i < 4; ++i)
#pragma unroll
    for (int j = 0; j < 4; ++j) acc[i][j] = (f32x4){0.f, 0.f, 0.f, 0.f};

  auto stage = [&](int buf, int h) {   // 4 async B loads
    char* lb = (char*)&Bs[buf][0];
#pragma unroll
    for (int it = 0; it < 4; ++it)
      async_copy16(lb + b_dst[it], WbB + b_src[it] + (size_t)h * 128);
  };

  auto loadA = [&](bf16x8 (&ar)[4][2], int t) {  // 8 per-lane dwordx4 loads
#pragma unroll
    for (int mf = 0; mf < 4; ++mf)
#pragma unroll
      for (int kk = 0; kk < 2; ++kk)
        ar[mf][kk] = *(const bf16x8*)(Xb + a_g[mf] + (size_t)t * 4096 + kk * 32);
  };

  bf16x8 aA[4][2], aB[4][2];
  int cur = 0, pre = 2;

  // one K-step: round-3 proven 2-phase barrier skeleton
  auto step = [&](int t, bf16x8 (&aC)[4][2], bf16x8 (&aN)[4][2]) {
    const char* bb = (const char*)&Bs[cur][0];
    __builtin_amdgcn_sched_barrier(0);
    // ===== phase 0 (kk=0): issue A(t+1), read B frags, MFMA =====
    if (t + 1 < 64) loadA(aN, t + 1);
    bf16x8 bfr0[4];
#pragma unroll
    for (int f = 0; f < 4; ++f) bfr0[f] = *(const bf16x8*)(bb + b_ro[0][f]);
    __builtin_amdgcn_s_barrier();
    __builtin_amdgcn_s_setprio(1);
#pragma unroll
    for (int mf = 0; mf < 4; ++mf)
#pragma unroll
      for (int nf = 0; nf < 4; ++nf)
        acc[mf][nf] = __builtin_amdgcn_mfma_f32_16x16x32_bf16(
            aC[mf][0], bfr0[nf], acc[mf][nf], 0, 0, 0);
    __builtin_amdgcn_s_setprio(0);
    __builtin_amdgcn_s_barrier();

    // ===== phase 1 (kk=1): read B frags, issue B-stage(t+2), MFMA =====
    __builtin_amdgcn_sched_barrier(0);
    bf16x8 bfr1[4];
#pragma unroll
    for (int f = 0; f < 4; ++f) bfr1[f] = *(const bf16x8*)(bb + b_ro[1][f]);
    asm volatile("" ::: "memory");  // pin: A(t+1) issues precede B(t+2) copies
    if (t + 2 < 64) stage(pre, t + 2);
    __builtin_amdgcn_s_barrier();
    __builtin_amdgcn_s_setprio(1);
#pragma unroll
    for (int mf = 0; mf < 4; ++mf)
#pragma unroll
      for (int nf = 0; nf < 4; ++nf)
        acc[mf][nf] = __builtin_amdgcn_mfma_f32_16x16x32_bf16(
            aC[mf][1], bfr1[nf], acc[mf][nf], 0, 0, 0);
    __builtin_amdgcn_s_setprio(0);
    // boundary: drain B(t+1)+A(t+1), keep B(t+2)'s 4 loads in flight
    asm volatile("s_waitcnt lgkmcnt(0)" ::: "memory");
    if (t < 62) {
      asm volatile("s_waitcnt vmcnt(4)" ::: "memory");
    } else if (t == 62) {
      asm volatile("s_waitcnt vmcnt(0)" ::: "memory");
    }
    __builtin_amdgcn_s_barrier();
    cur = (cur == 2) ? 0 : cur + 1;
    pre = (pre == 2) ? 0 : pre + 1;
  };

  // ---- prologue: order = B(0), A(0), B(1) so vmcnt(4) keeps B(1) in flight ----
  stage(0, 0);
  loadA(aA, 0);
  asm volatile("" ::: "memory");
  stage(1, 1);
  asm volatile("s_waitcnt vmcnt(4)" ::: "memory");
  __builtin_amdgcn_s_barrier();

  // ---- main loop, 2x-unrolled for static A-reg double buffering ----
  for (int t = 0; t < 64; t += 2) {
    step(t, aA, aB);
    step(t + 1, aB, aA);
  }

  // ---- epilogue: relu + scatter to y[b, i=nt, j, u] ----
  const int rbase = (lane >> 4) * 4;
  const int cn = lane & 15;
#pragma unroll
  for (int mf = 0; mf < 4; ++mf) {
#pragma unroll
    for (int r = 0; r < 4; ++r) {
      const int ml = wm * 64 + mf * 16 + rbase + r;
      const int m = mt * 128 + ml;
      const int b = m >> 6;
      const int j = m & 63;
      float* orow = O + (((size_t)b * 64 + nt) * 64 + j) * 128;
#pragma unroll
      for (int nf = 0; nf < 4; ++nf) {
        const int u = wn * 64 + nf * 16 + cn;
        orow[u] = fmaxf(acc[mf][nf][r], 0.f);
      }
    }
  }
}

// ---------------- Fallback (round-1 fused kernel, used only if ws too small) ----
__global__ __launch_bounds__(256, 2)
void fused_gemm(const float* __restrict__ X, const float* __restrict__ Wt,
                float* __restrict__ O) {
  __shared__ ushort_t As[2][128 * 64];
  __shared__ ushort_t Bs[2][128 * 64];
  const int tid = threadIdx.x;
  const int lane = tid & 63;
  const int wid = tid >> 6;
  const int wm = wid >> 1;
  const int wn = wid & 1;
  const int bid = blockIdx.x;
  const int wg = (bid & 7) * 64 + (bid >> 3);
  const int mt = wg & 7;
  const int nt = wg >> 3;
  const int a_ml = tid >> 1;
  const int a_hp = (tid & 1) * 2;
  const int a_b = (mt * 128 + a_ml) >> 6;
  const int a_j = a_ml & 63;
  const float* a_base = X + ((size_t)a_b << 18) + ((size_t)a_j << 6);
  const int b_nl = tid >> 1;
  const int b_c8 = (tid & 1) * 8;
  const float* b_base = Wt + ((size_t)b_nl << 18) + ((size_t)nt << 6);
  f32x4 ra[2][4];
  f32x4 rb[8];
  f32x4 acc[4][4];
#pragma unroll
  for (int i = 0; i < 4; ++i)
#pragma unroll
    for (int j = 0; j < 4; ++j) acc[i][j] = (f32x4){0.f, 0.f, 0.f, 0.f};
  auto stage_load = [&](int t) {
    const int th = t & 15;
    const int tc = t >> 4;
    const int c0 = tc * 16;
    const int h0 = th * 4;
#pragma unroll
    for (int s = 0; s < 2; ++s) {
      const float* p = a_base + (size_t)(h0 + a_hp + s) * 4096 + c0;
#pragma unroll
      for (int q = 0; q < 4; ++q) ra[s][q] = ((const f32x4*)p)[q];
    }
#pragma unroll
    for (int q = 0; q < 8; ++q)
      rb[q] = *(const f32x4*)(b_base + (size_t)(c0 + b_c8 + q) * 4096 + h0);
  };
  auto stage_write = [&](int buf) {
    char* abase = (char*)&As[buf][0];
    const int swa = (a_ml & 7) << 4;
#pragma unroll
    for (int s = 0; s < 2; ++s) {
      u32x4 lo, hi;
      lo.x = cvt_pk_bf16(ra[s][0].x, ra[s][0].y);
      lo.y = cvt_pk_bf16(ra[s][0].z, ra[s][0].w);
      lo.z = cvt_pk_bf16(ra[s][1].x, ra[s][1].y);
      lo.w = cvt_pk_bf16(ra[s][1].z, ra[s][1].w);
      hi.x = cvt_pk_bf16(ra[s][2].x, ra[s][2].y);
      hi.y = cvt_pk_bf16(ra[s][2].z, ra[s][2].w);
      hi.z = cvt_pk_bf16(ra[s][3].x, ra[s][3].y);
      hi.w = cvt_pk_bf16(ra[s][3].z, ra[s][3].w);
      const int byte0 = a_ml * 128 + (a_hp + s) * 32;
      *(u32x4*)(abase + (byte0 ^ swa)) = lo;
      *(u32x4*)(abase + ((byte0 + 16) ^ swa)) = hi;
    }
    char* bbase = (char*)&Bs[buf][0];
    const int swb = (b_nl & 7) << 4;
#pragma unroll
    for (int hl = 0; hl < 4; ++hl) {
      u32x4 v;
      v.x = cvt_pk_bf16(rb[0][hl], rb[1][hl]);
      v.y = cvt_pk_bf16(rb[2][hl], rb[3][hl]);
      v.z = cvt_pk_bf16(rb[4][hl], rb[5][hl]);
      v.w = cvt_pk_bf16(rb[6][hl], rb[7][hl]);
      const int byte0 = b_nl * 128 + (hl * 16 + b_c8) * 2;
      *(u32x4*)(bbase + (byte0 ^ swb)) = v;
    }
  };
  auto compute = [&](int buf) {
    const char* abase = (const char*)&As[buf][0];
    const char* bbase = (const char*)&Bs[buf][0];
#pragma unroll
    for (int kk = 0; kk < 2; ++kk) {
      bf16x8 af[4], bfr[4];
#pragma unroll
      for (int mf = 0; mf < 4; ++mf) {
        const int row = wm * 64 + mf * 16 + (lane & 15);
        const int byte0 = row * 128 + kk * 64 + (lane >> 4) * 16;
        af[mf] = *(const bf16x8*)(abase + (byte0 ^ ((row & 7) << 4)));
      }
#pragma unroll
      for (int nf = 0; nf < 4; ++nf) {
        const int row = wn * 64 + nf * 16 + (lane & 15);
        const int byte0 = row * 128 + kk * 64 + (lane >> 4) * 16;
        bfr[nf] = *(const bf16x8*)(bbase + (byte0 ^ ((row & 7) << 4)));
      }
#pragma unroll
      for (int mf = 0; mf < 4; ++mf)
#pragma unroll
        for (int nf = 0; nf < 4; ++nf)
          acc[mf][nf] = __builtin_amdgcn_mfma_f32_16x16x32_bf16(
              af[mf], bfr[nf], acc[mf][nf], 0, 0, 0);
    }
  };
  stage_load(0);
  stage_write(0);
  __syncthreads();
  int cur = 0;
  for (int t = 0; t < 64; ++t) {
    if (t + 1 < 64) stage_load(t + 1);
    compute(cur);
    if (t + 1 < 64) stage_write(cur ^ 1);
    __syncthreads();
    cur ^= 1;
  }
  const int rbase = (lane >> 4) * 4;
  const int cn = lane & 15;
#pragma unroll
  for (int mf = 0; mf < 4; ++mf) {
#pragma unroll
    for (int r = 0; r < 4; ++r) {
      const int ml = wm * 64 + mf * 16 + rbase + r;
      const int m = mt * 128 + ml;
      const int b = m >> 6;
      const int j = m & 63;
      float* orow = O + (((size_t)b * 64 + nt) * 64 + j) * 128;
#pragma unroll
      for (int nf = 0; nf < 4; ++nf) {
        const int u = wn * 64 + nf * 16 + cn;
        orow[u] = fmaxf(acc[mf][nf][r], 0.f);
      }
    }
  }
}

extern "C" void kernel_launch(void* const* d_in, const int* in_sizes, int n_in,
                              void* d_out, int out_size, void* d_ws, size_t ws_size,
                              hipStream_t stream) {
  const float* x = (const float*)d_in[0];   // (16,64,64,64) f32
  const float* w = (const float*)d_in[1];   // (128,64,64,64) f32
  float* out = (float*)d_out;               // (16,64,64,128) f32

  const size_t XB_BYTES = (size_t)16 * 64 * 64 * 64 * 2;    // 8,388,608
  const size_t WB_BYTES = (size_t)64 * 128 * 64 * 64 * 2;   // 67,108,864

  if (ws_size >= XB_BYTES + WB_BYTES) {
    ushort_t* Xb = (ushort_t*)d_ws;
    ushort_t* Wb = (ushort_t*)((char*)d_ws + XB_BYTES);
    hipLaunchKernelGGL(conv_x, dim3(1024), dim3(256), 0, stream, x, Xb,
                       (int)(16 * 64 * 64 * 64 / 4));
    hipLaunchKernelGGL(conv_w, dim3(8192), dim3(256), 0, stream, w, Wb);
    hipLaunchKernelGGL(gemm4, dim3(512), dim3(256), 0, stream, Xb, Wb, out);
  } else {
    hipLaunchKernelGGL(fused_gemm, dim3(512), dim3(256), 0, stream, x, w, out);
  }
}

// Round 6
// 107.006 us; speedup vs baseline: 1.6754x; 1.6754x over previous
//
#include <hip/hip_runtime.h>
#include <hip/hip_bf16.h>

// y[b,i,j,u] = relu( sum_{c,h} w[u,c,i,h] * x[b,h,j,c] )
// B=16,H=64,W=64,C=64,U=128
// GEMM: M=(b,j)=1024, N=(i,u)=8192 (n=i*128+u), K=(h,c)=4096, kappa=h*64+c.
//
// Pass 1a: Xb[b][h][j][c] = bf16(x)                      (8.39 MB, ws+0)
// Pass 1b: Wb[i][u][h][c] = bf16(w[u][c][i][h])          (64 MB,  ws+8388608)
// Pass 2 : BM=128 x BN=256 x BK=64, 8 waves, triple-buffered LDS,
//          counted s_waitcnt vmcnt (T4), 2-phase barrier skeleton + setprio
//          (T5), and READ-AHEAD fragment pipelining: each phase's MFMA uses
//          fragments ds_read-issued one phase earlier (counted lgkm), so LDS
//          service overlaps the MFMA cluster. XOR swizzle (T2), XCD swizzle
//          (T1). Grid=256 blocks = 1/CU.

typedef __attribute__((ext_vector_type(4))) float f32x4;
typedef __attribute__((ext_vector_type(8))) short bf16x8;
typedef __attribute__((ext_vector_type(4))) unsigned int u32x4;
typedef __attribute__((ext_vector_type(2))) unsigned int u32x2;
typedef unsigned short ushort_t;

static __device__ __forceinline__ unsigned int cvt_pk_bf16(float lo, float hi) {
  unsigned int r;
  asm("v_cvt_pk_bf16_f32 %0, %1, %2" : "=v"(r) : "v"(lo), "v"(hi));
  return r;
}

static __device__ __forceinline__ void async_copy16(void* lds, const void* g) {
  __builtin_amdgcn_global_load_lds(
      (const __attribute__((address_space(1))) unsigned int*)g,
      (__attribute__((address_space(3))) unsigned int*)lds, 16, 0, 0);
}

// ---------------- Pass 1a: x f32 -> bf16 (straight) ----------------
__global__ __launch_bounds__(256)
void conv_x(const float* __restrict__ X, ushort_t* __restrict__ Xb, int n4) {
  int idx = blockIdx.x * 256 + threadIdx.x;
  const int stride = gridDim.x * 256;
  for (; idx < n4; idx += stride) {
    f32x4 v = ((const f32x4*)X)[idx];
    u32x2 o;
    o.x = cvt_pk_bf16(v.x, v.y);
    o.y = cvt_pk_bf16(v.z, v.w);
    ((u32x2*)Xb)[idx] = o;
  }
}

// ---------------- Pass 1b: w[u][c][i][h] -> Wb[i][u][h][c] bf16 ----------------
__global__ __launch_bounds__(256)
void conv_w(const float* __restrict__ W, ushort_t* __restrict__ Wb) {
  __shared__ float T[64][65];  // [c][h], +1 pad
  const int bid = blockIdx.x;       // 8192 blocks = u*64 + i
  const int u = bid >> 6;
  const int i = bid & 63;
  const int t = threadIdx.x;

  const int hq = t & 15;            // 16B chunk of h-row
  const int c4 = t >> 4;            // 0..15
  const float* base = W + (((size_t)u * 64) * 64 + i) * 64;  // + c*4096 + h
#pragma unroll
  for (int it = 0; it < 4; ++it) {
    const int c = it * 16 + c4;
    f32x4 v = *(const f32x4*)(base + (size_t)c * 4096 + hq * 4);
    *(f32x4*)&T[c][hq * 4] = v;
  }
  __syncthreads();

  const int h = t >> 2;
  const int c0 = (t & 3) * 16;
  unsigned int pk[8];
#pragma unroll
  for (int q = 0; q < 8; ++q)
    pk[q] = cvt_pk_bf16(T[c0 + 2 * q][h], T[c0 + 2 * q + 1][h]);
  ushort_t* out = Wb + (((size_t)i * 128 + u) * 64 + h) * 64 + c0;
  ((u32x4*)out)[0] = *(u32x4*)&pk[0];
  ((u32x4*)out)[1] = *(u32x4*)&pk[4];
}

// ---------------- Pass 2: bf16 GEMM, read-ahead 2-phase schedule ------------
__global__ __launch_bounds__(512, 2)
void gemm8(const ushort_t* __restrict__ Xb, const ushort_t* __restrict__ Wb,
           float* __restrict__ O) {
  __shared__ ushort_t As[3][128 * 64];  // 16KB each, XOR-swizzled rows
  __shared__ ushort_t Bs[3][256 * 64];  // 32KB each

  const int tid = threadIdx.x;
  const int lane = tid & 63;
  const int wid = tid >> 6;
  const int wm = wid >> 2;          // 0..1 : 64-row m slab
  const int wn = wid & 3;           // 0..3 : 64-col n slab

  const int bid = blockIdx.x;       // 256 blocks; XCD-bijective swizzle
  const int wg = (bid & 7) * 32 + (bid >> 3);
  const int mt = wg & 7;            // 8 m-tiles of 128
  const int nt2 = wg >> 3;          // 32 n-tiles of 256 (an i-pair)

  const char* XbB = (const char*)Xb;
  const char* WbB = (const char*)Wb;

  // ---- staging geometry: LDS dest lane-linear, source carries the XOR ----
  int a_dst[2]; size_t a_src[2];
#pragma unroll
  for (int it = 0; it < 2; ++it) {
    const int flat = it * 8192 + tid * 16;
    const int row = flat >> 7;            // m_local
    const int p = (flat >> 4) & 7;        // physical 16B slot
    const int b = mt * 2 + (row >> 6);
    const int j = row & 63;
    a_dst[it] = flat;
    a_src[it] = (size_t)b * 524288 + (size_t)j * 128 + ((p ^ (row & 7)) << 4);
  }
  int b_dst[4]; size_t b_src[4];
#pragma unroll
  for (int it = 0; it < 4; ++it) {
    const int flat = it * 8192 + tid * 16;
    const int nl = flat >> 7;             // n_local 0..255
    const int p = (flat >> 4) & 7;
    b_dst[it] = flat;
    b_src[it] = (size_t)(nt2 * 256 + nl) * 8192 + ((p ^ (nl & 7)) << 4);
  }

  // ---- fragment ds_read offsets (buffer-relative, per kk) ----
  int a_ro[2][4], b_ro[2][4];
#pragma unroll
  for (int kk = 0; kk < 2; ++kk) {
#pragma unroll
    for (int f = 0; f < 4; ++f) {
      int row = wm * 64 + f * 16 + (lane & 15);
      int byte0 = row * 128 + kk * 64 + (lane >> 4) * 16;
      a_ro[kk][f] = byte0 ^ ((row & 7) << 4);
      row = wn * 64 + f * 16 + (lane & 15);
      byte0 = row * 128 + kk * 64 + (lane >> 4) * 16;
      b_ro[kk][f] = byte0 ^ ((row & 7) << 4);
    }
  }

  f32x4 acc[4][4];
#pragma unroll
  for (int i = 0; i < 4; ++i)
#pragma unroll
    for (int j = 0; j < 4; ++j) acc[i][j] = (f32x4){0.f, 0.f, 0.f, 0.f};

  auto stage = [&](int buf, int h) {      // all 6 loads (prologue only)
    char* la = (char*)&As[buf][0];
    char* lb = (char*)&Bs[buf][0];
#pragma unroll
    for (int it = 0; it < 2; ++it)
      async_copy16(la + a_dst[it], XbB + a_src[it] + (size_t)h * 8192);
#pragma unroll
    for (int it = 0; it < 4; ++it)
      async_copy16(lb + b_dst[it], WbB + b_src[it] + (size_t)h * 128);
  };
  auto stage3a = [&](int buf, int h) {    // 2 A + 1 B
    char* la = (char*)&As[buf][0];
    char* lb = (char*)&Bs[buf][0];
#pragma unroll
    for (int it = 0; it < 2; ++it)
      async_copy16(la + a_dst[it], XbB + a_src[it] + (size_t)h * 8192);
    async_copy16(lb + b_dst[0], WbB + b_src[0] + (size_t)h * 128);
  };
  auto stage3b = [&](int buf, int h) {    // 3 B
    char* lb = (char*)&Bs[buf][0];
#pragma unroll
    for (int it = 1; it < 4; ++it)
      async_copy16(lb + b_dst[it], WbB + b_src[it] + (size_t)h * 128);
  };

  // fragment register sets: f*0 hold kk=0 frags, f*1 hold kk=1 frags
  bf16x8 fa0[4], fb0[4], fa1[4], fb1[4];

  auto readFrags = [&](bf16x8 (&fa)[4], bf16x8 (&fb)[4], int buf, int kk) {
    const char* ab = (const char*)&As[buf][0];
    const char* bb = (const char*)&Bs[buf][0];
#pragma unroll
    for (int f = 0; f < 4; ++f) fa[f] = *(const bf16x8*)(ab + a_ro[kk][f]);
#pragma unroll
    for (int f = 0; f < 4; ++f) fb[f] = *(const bf16x8*)(bb + b_ro[kk][f]);
  };

  // ---- prologue: stage tiles 0,1; wait tile 0; preload kk0 frags of tile 0 ----
  stage(0, 0);
  stage(1, 1);
  asm volatile("s_waitcnt vmcnt(6)" ::: "memory");
  __builtin_amdgcn_s_barrier();
  readFrags(fa0, fb0, 0, 0);

  int cur = 0, nxt = 1, pre = 2;
  for (int t = 0; t < 64; ++t) {
    // ===== phase 0: compute kk=0 (preloaded), preload kk=1 of tile t =====
    __builtin_amdgcn_sched_barrier(0);
    readFrags(fa1, fb1, cur, 1);
    if (t + 2 < 64) stage3a(pre, t + 2);
    // drain tile t+1's 6 staging loads (issued last step); keep the 3 newest
    if (t < 62) {
      asm volatile("s_waitcnt vmcnt(3)" ::: "memory");
    } else {
      asm volatile("s_waitcnt vmcnt(0)" ::: "memory");
    }
    __builtin_amdgcn_sched_barrier(0);
    __builtin_amdgcn_s_barrier();
    __builtin_amdgcn_s_setprio(1);
#pragma unroll
    for (int mf = 0; mf < 4; ++mf)
#pragma unroll
      for (int nf = 0; nf < 4; ++nf)
        acc[mf][nf] = __builtin_amdgcn_mfma_f32_16x16x32_bf16(
            fa0[mf], fb0[nf], acc[mf][nf], 0, 0, 0);
    __builtin_amdgcn_s_setprio(0);
    __builtin_amdgcn_s_barrier();

    // ===== phase 1: compute kk=1, preload kk=0 of tile t+1 from buf[nxt] =====
    __builtin_amdgcn_sched_barrier(0);
    if (t + 1 < 64) readFrags(fa0, fb0, nxt, 0);
    if (t + 2 < 64) stage3b(pre, t + 2);
    __builtin_amdgcn_sched_barrier(0);
    __builtin_amdgcn_s_barrier();
    __builtin_amdgcn_s_setprio(1);
#pragma unroll
    for (int mf = 0; mf < 4; ++mf)
#pragma unroll
      for (int nf = 0; nf < 4; ++nf)
        acc[mf][nf] = __builtin_amdgcn_mfma_f32_16x16x32_bf16(
            fa1[mf], fb1[nf], acc[mf][nf], 0, 0, 0);
    __builtin_amdgcn_s_setprio(0);
    __builtin_amdgcn_s_barrier();

    cur = (cur == 2) ? 0 : cur + 1;
    nxt = (nxt == 2) ? 0 : nxt + 1;
    pre = (pre == 2) ? 0 : pre + 1;
  }

  // ---- epilogue: relu + scatter to y[b, i, j, u] ----
  const int rbase = (lane >> 4) * 4;
  const int cn = lane & 15;
#pragma unroll
  for (int mf = 0; mf < 4; ++mf) {
#pragma unroll
    for (int r = 0; r < 4; ++r) {
      const int ml = wm * 64 + mf * 16 + rbase + r;
      const int m = mt * 128 + ml;
      const int b = m >> 6;
      const int j = m & 63;
#pragma unroll
      for (int nf = 0; nf < 4; ++nf) {
        const int nloc = wn * 64 + nf * 16 + cn;
        const int i = nt2 * 2 + (nloc >> 7);
        const int u = nloc & 127;
        O[(((size_t)b * 64 + i) * 64 + j) * 128 + u] = fmaxf(acc[mf][nf][r], 0.f);
      }
    }
  }
}

// ---------------- Fallback (round-1 fused kernel, used only if ws too small) ----
__global__ __launch_bounds__(256, 2)
void fused_gemm(const float* __restrict__ X, const float* __restrict__ Wt,
                float* __restrict__ O) {
  __shared__ ushort_t As[2][128 * 64];
  __shared__ ushort_t Bs[2][128 * 64];
  const int tid = threadIdx.x;
  const int lane = tid & 63;
  const int wid = tid >> 6;
  const int wm = wid >> 1;
  const int wn = wid & 1;
  const int bid = blockIdx.x;
  const int wg = (bid & 7) * 64 + (bid >> 3);
  const int mt = wg & 7;
  const int nt = wg >> 3;
  const int a_ml = tid >> 1;
  const int a_hp = (tid & 1) * 2;
  const int a_b = (mt * 128 + a_ml) >> 6;
  const int a_j = a_ml & 63;
  const float* a_base = X + ((size_t)a_b << 18) + ((size_t)a_j << 6);
  const int b_nl = tid >> 1;
  const int b_c8 = (tid & 1) * 8;
  const float* b_base = Wt + ((size_t)b_nl << 18) + ((size_t)nt << 6);
  f32x4 ra[2][4];
  f32x4 rb[8];
  f32x4 acc[4][4];
#pragma unroll
  for (int i = 0; i < 4; ++i)
#pragma unroll
    for (int j = 0; j < 4; ++j) acc[i][j] = (f32x4){0.f, 0.f, 0.f, 0.f};
  auto stage_load = [&](int t) {
    const int th = t & 15;
    const int tc = t >> 4;
    const int c0 = tc * 16;
    const int h0 = th * 4;
#pragma unroll
    for (int s = 0; s < 2; ++s) {
      const float* p = a_base + (size_t)(h0 + a_hp + s) * 4096 + c0;
#pragma unroll
      for (int q = 0; q < 4; ++q) ra[s][q] = ((const f32x4*)p)[q];
    }
#pragma unroll
    for (int q = 0; q < 8; ++q)
      rb[q] = *(const f32x4*)(b_base + (size_t)(c0 + b_c8 + q) * 4096 + h0);
  };
  auto stage_write = [&](int buf) {
    char* abase = (char*)&As[buf][0];
    const int swa = (a_ml & 7) << 4;
#pragma unroll
    for (int s = 0; s < 2; ++s) {
      u32x4 lo, hi;
      lo.x = cvt_pk_bf16(ra[s][0].x, ra[s][0].y);
      lo.y = cvt_pk_bf16(ra[s][0].z, ra[s][0].w);
      lo.z = cvt_pk_bf16(ra[s][1].x, ra[s][1].y);
      lo.w = cvt_pk_bf16(ra[s][1].z, ra[s][1].w);
      hi.x = cvt_pk_bf16(ra[s][2].x, ra[s][2].y);
      hi.y = cvt_pk_bf16(ra[s][2].z, ra[s][2].w);
      hi.z = cvt_pk_bf16(ra[s][3].x, ra[s][3].y);
      hi.w = cvt_pk_bf16(ra[s][3].z, ra[s][3].w);
      const int byte0 = a_ml * 128 + (a_hp + s) * 32;
      *(u32x4*)(abase + (byte0 ^ swa)) = lo;
      *(u32x4*)(abase + ((byte0 + 16) ^ swa)) = hi;
    }
    char* bbase = (char*)&Bs[buf][0];
    const int swb = (b_nl & 7) << 4;
#pragma unroll
    for (int hl = 0; hl < 4; ++hl) {
      u32x4 v;
      v.x = cvt_pk_bf16(rb[0][hl], rb[1][hl]);
      v.y = cvt_pk_bf16(rb[2][hl], rb[3][hl]);
      v.z = cvt_pk_bf16(rb[4][hl], rb[5][hl]);
      v.w = cvt_pk_bf16(rb[6][hl], rb[7][hl]);
      const int byte0 = b_nl * 128 + (hl * 16 + b_c8) * 2;
      *(u32x4*)(bbase + (byte0 ^ swb)) = v;
    }
  };
  auto compute = [&](int buf) {
    const char* abase = (const char*)&As[buf][0];
    const char* bbase = (const char*)&Bs[buf][0];
#pragma unroll
    for (int kk = 0; kk < 2; ++kk) {
      bf16x8 af[4], bfr[4];
#pragma unroll
      for (int mf = 0; mf < 4; ++mf) {
        const int row = wm * 64 + mf * 16 + (lane & 15);
        const int byte0 = row * 128 + kk * 64 + (lane >> 4) * 16;
        af[mf] = *(const bf16x8*)(abase + (byte0 ^ ((row & 7) << 4)));
      }
#pragma unroll
      for (int nf = 0; nf < 4; ++nf) {
        const int row = wn * 64 + nf * 16 + (lane & 15);
        const int byte0 = row * 128 + kk * 64 + (lane >> 4) * 16;
        bfr[nf] = *(const bf16x8*)(bbase + (byte0 ^ ((row & 7) << 4)));
      }
#pragma unroll
      for (int mf = 0; mf < 4; ++mf)
#pragma unroll
        for (int nf = 0; nf < 4; ++nf)
          acc[mf][nf] = __builtin_amdgcn_mfma_f32_16x16x32_bf16(
              af[mf], bfr[nf], acc[mf][nf], 0, 0, 0);
    }
  };
  stage_load(0);
  stage_write(0);
  __syncthreads();
  int cur = 0;
  for (int t = 0; t < 64; ++t) {
    if (t + 1 < 64) stage_load(t + 1);
    compute(cur);
    if (t + 1 < 64) stage_write(cur ^ 1);
    __syncthreads();
    cur ^= 1;
  }
  const int rbase = (lane >> 4) * 4;
  const int cn = lane & 15;
#pragma unroll
  for (int mf = 0; mf < 4; ++mf) {
#pragma unroll
    for (int r = 0; r < 4; ++r) {
      const int ml = wm * 64 + mf * 16 + rbase + r;
      const int m = mt * 128 + ml;
      const int b = m >> 6;
      const int j = m & 63;
      float* orow = O + (((size_t)b * 64 + nt) * 64 + j) * 128;
#pragma unroll
      for (int nf = 0; nf < 4; ++nf) {
        const int u = wn * 64 + nf * 16 + cn;
        orow[u] = fmaxf(acc[mf][nf][r], 0.f);
      }
    }
  }
}

extern "C" void kernel_launch(void* const* d_in, const int* in_sizes, int n_in,
                              void* d_out, int out_size, void* d_ws, size_t ws_size,
                              hipStream_t stream) {
  const float* x = (const float*)d_in[0];   // (16,64,64,64) f32
  const float* w = (const float*)d_in[1];   // (128,64,64,64) f32
  float* out = (float*)d_out;               // (16,64,64,128) f32

  const size_t XB_BYTES = (size_t)16 * 64 * 64 * 64 * 2;    // 8,388,608
  const size_t WB_BYTES = (size_t)64 * 128 * 64 * 64 * 2;   // 67,108,864

  if (ws_size >= XB_BYTES + WB_BYTES) {
    ushort_t* Xb = (ushort_t*)d_ws;
    ushort_t* Wb = (ushort_t*)((char*)d_ws + XB_BYTES);
    hipLaunchKernelGGL(conv_x, dim3(1024), dim3(256), 0, stream, x, Xb,
                       (int)(16 * 64 * 64 * 64 / 4));
    hipLaunchKernelGGL(conv_w, dim3(8192), dim3(256), 0, stream, w, Wb);
    hipLaunchKernelGGL(gemm8, dim3(256), dim3(512), 0, stream, Xb, Wb, out);
  } else {
    hipLaunchKernelGGL(fused_gemm, dim3(512), dim3(256), 0, stream, x, w, out);
  }
}